// Round 1
// baseline (1687.313 us; speedup 1.0000x reference)
//
#include <hip/hip_runtime.h>
#include <math.h>

#define SEQ 2048
#define DMODEL 1024
#define NHEADS 16
#define DHEAD 64

typedef long long i64;

// ---------------------------------------------------------------------------
// Generic TN GEMM: C = A(MxK, lda) * B(NxK, ldb)^T
// Tile 64x64, BK=16, 256 threads, 4x4 per thread, f32.
// mode 0: plain store C[m*ldc+n]
// mode 1: head-layout store C[((n>>6)*SEQ + m)*64 + (n&63)]
// mode 2: like 1 but writes C = acc + bu[n], C2 = acc + bv[n]
// mode 3: plain store with exact GELU epilogue
// ---------------------------------------------------------------------------
__global__ __launch_bounds__(256)
void gemm_tn(const float* __restrict__ A, int lda,
             const float* __restrict__ B, int ldb,
             float* __restrict__ C, int ldc,
             int M, int N, int K, int mode,
             const float* __restrict__ bu,
             const float* __restrict__ bv,
             float* __restrict__ C2)
{
    __shared__ float As[16][64];
    __shared__ float Bs[16][64];
    const int tid = threadIdx.x;
    const int tx = tid & 15, ty = tid >> 4;
    const int m0 = blockIdx.y * 64, n0 = blockIdx.x * 64;
    const int lrow = tid >> 2;           // 0..63
    const int lcol = (tid & 3) << 2;     // 0,4,8,12
    const float* Ap = A + (i64)(m0 + lrow) * lda + lcol;
    const float* Bp = B + (i64)(n0 + lrow) * ldb + lcol;
    float acc[4][4] = {{0.f}};

    for (int k0 = 0; k0 < K; k0 += 16) {
        const float4 a4 = *(const float4*)(Ap + k0);
        const float4 b4 = *(const float4*)(Bp + k0);
        __syncthreads();
        As[lcol+0][lrow] = a4.x; As[lcol+1][lrow] = a4.y;
        As[lcol+2][lrow] = a4.z; As[lcol+3][lrow] = a4.w;
        Bs[lcol+0][lrow] = b4.x; Bs[lcol+1][lrow] = b4.y;
        Bs[lcol+2][lrow] = b4.z; Bs[lcol+3][lrow] = b4.w;
        __syncthreads();
#pragma unroll
        for (int kk = 0; kk < 16; ++kk) {
            float a[4], b[4];
#pragma unroll
            for (int q = 0; q < 4; ++q) { a[q] = As[kk][ty*4+q]; b[q] = Bs[kk][tx*4+q]; }
#pragma unroll
            for (int ii = 0; ii < 4; ++ii)
#pragma unroll
                for (int jj = 0; jj < 4; ++jj)
                    acc[ii][jj] = fmaf(a[ii], b[jj], acc[ii][jj]);
        }
    }

    if (mode == 0) {
#pragma unroll
        for (int ii = 0; ii < 4; ++ii)
#pragma unroll
            for (int jj = 0; jj < 4; ++jj)
                C[(i64)(m0+ty*4+ii)*ldc + (n0+tx*4+jj)] = acc[ii][jj];
    } else if (mode == 1 || mode == 2) {
#pragma unroll
        for (int ii = 0; ii < 4; ++ii)
#pragma unroll
            for (int jj = 0; jj < 4; ++jj) {
                const int m = m0 + ty*4 + ii;
                const int n = n0 + tx*4 + jj;
                const int h = n >> 6, d = n & 63;
                const i64 o = ((i64)h * SEQ + m) * DHEAD + d;
                if (mode == 1) {
                    C[o] = acc[ii][jj];
                } else {
                    C[o]  = acc[ii][jj] + bu[n];
                    C2[o] = acc[ii][jj] + bv[n];
                }
            }
    } else { // mode 3: exact GELU
#pragma unroll
        for (int ii = 0; ii < 4; ++ii)
#pragma unroll
            for (int jj = 0; jj < 4; ++jj) {
                const float x = acc[ii][jj];
                const float g = 0.5f * x * (1.f + erff(x * 0.70710678118654752f));
                C[(i64)(m0+ty*4+ii)*ldc + (n0+tx*4+jj)] = g;
            }
    }
}

// ---------------------------------------------------------------------------
// NN GEMM for PV: O[m, h*64+n] = sum_f W[h][m][f] * V[h][f][n]
// ---------------------------------------------------------------------------
__global__ __launch_bounds__(256)
void gemm_nn_pv(const float* __restrict__ Wb, const float* __restrict__ Vb,
                float* __restrict__ O)
{
    const int h = blockIdx.z;
    const float* A = Wb + (i64)h * SEQ * SEQ;
    const float* B = Vb + (i64)h * SEQ * DHEAD;
    const int m0 = blockIdx.y * 64;
    __shared__ float As[16][64];
    __shared__ float Bs[16][64];
    const int tid = threadIdx.x;
    const int tx = tid & 15, ty = tid >> 4;
    const int lrow = tid >> 2, lcol = (tid & 3) << 2;   // A: 64 rows x 16 k
    const int brow = tid >> 4, bcol = (tid & 15) << 2;  // B: 16 k-rows x 64 cols
    float acc[4][4] = {{0.f}};

    for (int k0 = 0; k0 < SEQ; k0 += 16) {
        const float4 a4 = *(const float4*)(A + (i64)(m0+lrow)*SEQ + k0 + lcol);
        const float4 b4 = *(const float4*)(B + (i64)(k0+brow)*DHEAD + bcol);
        __syncthreads();
        As[lcol+0][lrow] = a4.x; As[lcol+1][lrow] = a4.y;
        As[lcol+2][lrow] = a4.z; As[lcol+3][lrow] = a4.w;
        *(float4*)&Bs[brow][bcol] = b4;
        __syncthreads();
#pragma unroll
        for (int kk = 0; kk < 16; ++kk) {
            float a[4], b[4];
#pragma unroll
            for (int q = 0; q < 4; ++q) { a[q] = As[kk][ty*4+q]; b[q] = Bs[kk][tx*4+q]; }
#pragma unroll
            for (int ii = 0; ii < 4; ++ii)
#pragma unroll
                for (int jj = 0; jj < 4; ++jj)
                    acc[ii][jj] = fmaf(a[ii], b[jj], acc[ii][jj]);
        }
    }
#pragma unroll
    for (int ii = 0; ii < 4; ++ii)
#pragma unroll
        for (int jj = 0; jj < 4; ++jj)
            O[(i64)(m0+ty*4+ii)*DMODEL + h*DHEAD + tx*4+jj] = acc[ii][jj];
}

// ---------------------------------------------------------------------------
// rel_enc[f, i] = pe[2047-f, i]; pe[P,i] = (i even ? sin : cos)(P * div_i)
// div_i = 10000^(-(i & ~1)/1024)
// ---------------------------------------------------------------------------
__global__ __launch_bounds__(256)
void posenc_kernel(float* __restrict__ RE)
{
    const int idx = blockIdx.x * 256 + threadIdx.x;
    const int f = idx >> 10;
    const int i = idx & 1023;
    const float P = (float)(SEQ - 1 - f);
    const float ex = (float)(i & ~1) * (1.f / 1024.f);
    const float dv = powf(10000.f, -ex);
    const float ang = P * dv;
    RE[idx] = (i & 1) ? cosf(ang) : sinf(ang);
}

// ---------------------------------------------------------------------------
// Row softmax over score row i of head h (in-place in weights region).
// score = (AC + B_D)/32 + mask;  B_D gathered from G rows i, i+1 (contiguous).
// Tracks per-head min of l (row max weight = 1/l).
// ---------------------------------------------------------------------------
__global__ __launch_bounds__(256)
void softmax_rows(float* __restrict__ Wh, const float* __restrict__ G,
                  const float* __restrict__ mask, unsigned int* __restrict__ lminh)
{
    __shared__ float red[4];
    const int i = blockIdx.x;
    const int tx = threadIdx.x;
    const i64 rowoff = (i64)i * SEQ;
    float s[8];
    float mloc = -3.0e38f;
#pragma unroll
    for (int r = 0; r < 8; ++r) {
        const int j = tx + (r << 8);
        float bd;
        if (j <= i)          bd = G[rowoff + (SEQ - 1 - i + j)];
        else if (j == i + 1) bd = 0.f;
        else                 bd = G[rowoff + SEQ + (j - i - 2)];
        const float v = (Wh[rowoff + j] + bd) * 0.03125f + mask[rowoff + j];
        s[r] = v;
        mloc = fmaxf(mloc, v);
    }
#pragma unroll
    for (int o = 32; o > 0; o >>= 1) mloc = fmaxf(mloc, __shfl_xor(mloc, o));
    if ((tx & 63) == 0) red[tx >> 6] = mloc;
    __syncthreads();
    const float m = fmaxf(fmaxf(red[0], red[1]), fmaxf(red[2], red[3]));
    __syncthreads();
    float lsum = 0.f;
#pragma unroll
    for (int r = 0; r < 8; ++r) { s[r] = __expf(s[r] - m); lsum += s[r]; }
#pragma unroll
    for (int o = 32; o > 0; o >>= 1) lsum += __shfl_xor(lsum, o);
    if ((tx & 63) == 0) red[tx >> 6] = lsum;
    __syncthreads();
    const float l = red[0] + red[1] + red[2] + red[3];
    const float inv = 1.f / l;
#pragma unroll
    for (int r = 0; r < 8; ++r) Wh[rowoff + tx + (r << 8)] = s[r] * inv;
    if (tx == 0) atomicMin(lminh, __float_as_uint(l));
}

__global__ void init_kernel(unsigned int* __restrict__ lmin)
{
    if (threadIdx.x < NHEADS) lmin[threadIdx.x] = 0x7F7FFFFFu; // FLT_MAX bits
}

__global__ void loss_kernel(const unsigned int* __restrict__ lmin, float* __restrict__ out)
{
    float v = 0.f;
    if (threadIdx.x < NHEADS) v = 1.f / __uint_as_float(lmin[threadIdx.x]);
#pragma unroll
    for (int o = 32; o > 0; o >>= 1) v += __shfl_xor(v, o);
    if (threadIdx.x == 0) *out = v * (1.f / NHEADS);
}

// ---------------------------------------------------------------------------
extern "C" void kernel_launch(void* const* d_in, const int* in_sizes, int n_in,
                              void* d_out, int out_size, void* d_ws, size_t ws_size,
                              hipStream_t stream)
{
    const float* query = (const float*)d_in[0];
    const float* key   = (const float*)d_in[1];
    const float* value = (const float*)d_in[2];
    const float* mask  = (const float*)d_in[3];
    const float* Wq    = (const float*)d_in[4];
    const float* Wke   = (const float*)d_in[5];
    const float* Wkr   = (const float*)d_in[6];
    const float* Wv    = (const float*)d_in[7];
    const float* Wf    = (const float*)d_in[8];
    const float* u_p   = (const float*)d_in[9];
    const float* v_p   = (const float*)d_in[10];

    float* out_final = (float*)d_out;                       // 2048*1024
    float* weights   = out_final + (i64)SEQ * DMODEL;       // 16*2048*2048
    float* loss      = weights + (i64)NHEADS * SEQ * SEQ;   // scalar

    const i64 HSD = (i64)SEQ * DHEAD * NHEADS;  // 2M floats
    float* qu = (float*)d_ws;
    float* qv = qu + HSD;
    float* kk = qv + HSD;
    float* vv = kk + HSD;
    float* rr = vv + HSD;
    float* scratch = rr + HSD;                  // rel_enc, later o_pre (2M floats)
    float* G  = scratch + (i64)SEQ * DMODEL;    // 4M floats
    unsigned int* lmin = (unsigned int*)(G + (i64)SEQ * SEQ);

    dim3 blk(256);
    init_kernel<<<dim3(1), dim3(64), 0, stream>>>(lmin);
    posenc_kernel<<<dim3((SEQ * DMODEL) / 256), blk, 0, stream>>>(scratch);

    dim3 gproj(DMODEL / 64, SEQ / 64);
    gemm_tn<<<gproj, blk, 0, stream>>>(query,   DMODEL, Wq,  DMODEL, qu, 0, SEQ, DMODEL, DMODEL, 2, u_p, v_p, qv);
    gemm_tn<<<gproj, blk, 0, stream>>>(key,     DMODEL, Wke, DMODEL, kk, 0, SEQ, DMODEL, DMODEL, 1, nullptr, nullptr, nullptr);
    gemm_tn<<<gproj, blk, 0, stream>>>(value,   DMODEL, Wv,  DMODEL, vv, 0, SEQ, DMODEL, DMODEL, 1, nullptr, nullptr, nullptr);
    gemm_tn<<<gproj, blk, 0, stream>>>(scratch, DMODEL, Wkr, DMODEL, rr, 0, SEQ, DMODEL, DMODEL, 1, nullptr, nullptr, nullptr);

    dim3 gattn(SEQ / 64, SEQ / 64);
    for (int h = 0; h < NHEADS; ++h) {
        const float* quh = qu + (i64)h * SEQ * DHEAD;
        const float* qvh = qv + (i64)h * SEQ * DHEAD;
        const float* kh  = kk + (i64)h * SEQ * DHEAD;
        const float* rh  = rr + (i64)h * SEQ * DHEAD;
        float* Wh = weights + (i64)h * SEQ * SEQ;
        gemm_tn<<<gattn, blk, 0, stream>>>(quh, DHEAD, kh, DHEAD, Wh, SEQ, SEQ, SEQ, DHEAD, 0, nullptr, nullptr, nullptr);
        gemm_tn<<<gattn, blk, 0, stream>>>(qvh, DHEAD, rh, DHEAD, G,  SEQ, SEQ, SEQ, DHEAD, 0, nullptr, nullptr, nullptr);
        softmax_rows<<<dim3(SEQ), blk, 0, stream>>>(Wh, G, mask, lmin + h);
    }

    gemm_nn_pv<<<dim3(1, SEQ / 64, NHEADS), blk, 0, stream>>>(weights, vv, scratch);
    gemm_tn<<<gproj, blk, 0, stream>>>(scratch, DMODEL, Wf, DMODEL, out_final, DMODEL, SEQ, DMODEL, DMODEL, 3, nullptr, nullptr, nullptr);
    loss_kernel<<<dim3(1), dim3(64), 0, stream>>>(lmin, loss);
}

// Round 2
// 1106.669 us; speedup vs baseline: 1.5247x; 1.5247x over previous
//
#include <hip/hip_runtime.h>
#include <math.h>

#define SEQ 2048
#define DMODEL 1024
#define NHEADS 16
#define DHEAD 64

typedef long long i64;
typedef unsigned short u16;
typedef __attribute__((ext_vector_type(4))) float f32x4;
typedef __attribute__((ext_vector_type(8))) short bf16x8;

#define IN_E  2097152   // 2048*1024
#define W_E   1048576   // 1024*1024
#define HEAD_E 131072   // 2048*64

// ---------------------------------------------------------------------------
// bf16 split helpers
// ---------------------------------------------------------------------------
__device__ inline u16 f2bf(float x) {                // RNE
    union { float f; unsigned u; } v; v.f = x;
    unsigned r = v.u + 0x7FFF + ((v.u >> 16) & 1);
    return (u16)(r >> 16);
}
__device__ inline float bf2f(u16 h) {
    union { unsigned u; float f; } v; v.u = ((unsigned)h) << 16;
    return v.f;
}

__device__ inline void gload16(const void* g, void* l) {
    __builtin_amdgcn_global_load_lds(
        (const __attribute__((address_space(1))) unsigned int*)g,
        (__attribute__((address_space(3))) unsigned int*)l, 16, 0, 0);
}

// ---------------------------------------------------------------------------
// Split 8 f32 arrays into bf16 hi/lo. z = array id, float4 per thread.
// ---------------------------------------------------------------------------
struct SplitArgs {
    const float* src[8];
    u16* dh[8];
    u16* dl[8];
    int n4[8];
};
__global__ __launch_bounds__(256)
void split_all(SplitArgs a)
{
    const int z = blockIdx.y;
    const int i = blockIdx.x * 256 + threadIdx.x;
    if (i >= a.n4[z]) return;
    const float4 x = ((const float4*)a.src[z])[i];
    u16 h0 = f2bf(x.x), h1 = f2bf(x.y), h2 = f2bf(x.z), h3 = f2bf(x.w);
    u16 l0 = f2bf(x.x - bf2f(h0)), l1 = f2bf(x.y - bf2f(h1));
    u16 l2 = f2bf(x.z - bf2f(h2)), l3 = f2bf(x.w - bf2f(h3));
    uint2 hh; hh.x = (unsigned)h0 | ((unsigned)h1 << 16); hh.y = (unsigned)h2 | ((unsigned)h3 << 16);
    uint2 ll; ll.x = (unsigned)l0 | ((unsigned)l1 << 16); ll.y = (unsigned)l2 | ((unsigned)l3 << 16);
    ((uint2*)a.dh[z])[i] = hh;
    ((uint2*)a.dl[z])[i] = ll;
}

// ---------------------------------------------------------------------------
// rel_enc computed + split directly
// ---------------------------------------------------------------------------
__global__ __launch_bounds__(256)
void posenc_split(u16* __restrict__ dh, u16* __restrict__ dl)
{
    const int idx = blockIdx.x * 256 + threadIdx.x;
    const int f = idx >> 10;
    const int i = idx & 1023;
    const float P = (float)(SEQ - 1 - f);
    const float ex = (float)(i & ~1) * (1.f / 1024.f);
    const float dv = powf(10000.f, -ex);
    const float ang = P * dv;
    const float val = (i & 1) ? cosf(ang) : sinf(ang);
    const u16 hb = f2bf(val);
    dh[idx] = hb;
    dl[idx] = f2bf(val - bf2f(hb));
}

// ---------------------------------------------------------------------------
// Split-3 bf16 MFMA TN GEMM, 128x128 tile, BK=32.
// C = A(MxK) * B(NxK)^T ; A/B pre-split into bf16 hi/lo.
// mode 0: f32 store C[z*sCz + m*ldc + n]
// mode 1: projection epilogue: head-layout split store to O1 (+bias1 if z==0);
//         if z==0 also O2 = acc + bias2 (split).
// mode 2: exact-GELU f32 store
// ---------------------------------------------------------------------------
struct TNArgs {
    const u16 *Ah, *Al, *Bh, *Bl;
    i64 sAz, sBz;
    float* Cf; i64 sCz; int ldc;
    u16 *O1h, *O1l, *O2h, *O2l;
    const float *b1, *b2;
    int K, mode;
};

__global__ __launch_bounds__(256)
void mfma_tn128(TNArgs p)
{
    __shared__ __align__(16) u16 Ash[128 * 32];
    __shared__ __align__(16) u16 Asl[128 * 32];
    __shared__ __align__(16) u16 Bsh[128 * 32];
    __shared__ __align__(16) u16 Bsl[128 * 32];
    const int tid = threadIdx.x, wave = tid >> 6, lane = tid & 63;
    const int z = blockIdx.z;
    const i64 m0 = (i64)blockIdx.y * 128, n0 = (i64)blockIdx.x * 128;
    const int K = p.K;
    const u16* Abh = p.Ah + (i64)z * p.sAz;
    const u16* Abl = p.Al + (i64)z * p.sAz;
    const u16* Bbh = p.Bh + (i64)z * p.sBz;
    const u16* Bbl = p.Bl + (i64)z * p.sBz;
    const int r0 = tid >> 2, kc = (tid & 3) * 8;   // inst0 row, col
    const int r1 = r0 + 64;                        // inst1 row
    u16* dA0 = &Ash[wave * 512];
    u16* dA1 = &Ash[2048 + wave * 512];
    u16* dA0l = &Asl[wave * 512];
    u16* dA1l = &Asl[2048 + wave * 512];
    u16* dB0 = &Bsh[wave * 512];
    u16* dB1 = &Bsh[2048 + wave * 512];
    u16* dB0l = &Bsl[wave * 512];
    u16* dB1l = &Bsl[2048 + wave * 512];
    const int wm = (wave >> 1) * 64, wn = (wave & 1) * 64;
    f32x4 acc[4][4] = {};

    for (int k0 = 0; k0 < K; k0 += 32) {
        __syncthreads();
        const i64 ga0 = (m0 + r0) * K + k0 + kc;
        const i64 ga1 = (m0 + r1) * K + k0 + kc;
        const i64 gb0 = (n0 + r0) * K + k0 + kc;
        const i64 gb1 = (n0 + r1) * K + k0 + kc;
        gload16(Abh + ga0, dA0);  gload16(Abh + ga1, dA1);
        gload16(Abl + ga0, dA0l); gload16(Abl + ga1, dA1l);
        gload16(Bbh + gb0, dB0);  gload16(Bbh + gb1, dB1);
        gload16(Bbl + gb0, dB0l); gload16(Bbl + gb1, dB1l);
        __syncthreads();
        const int fr = lane & 15, fk = (lane >> 4) * 8;
        bf16x8 fah[4], fal[4], fbh[4], fbl[4];
#pragma unroll
        for (int t = 0; t < 4; ++t) {
            fah[t] = *(const bf16x8*)&Ash[(wm + t * 16 + fr) * 32 + fk];
            fal[t] = *(const bf16x8*)&Asl[(wm + t * 16 + fr) * 32 + fk];
            fbh[t] = *(const bf16x8*)&Bsh[(wn + t * 16 + fr) * 32 + fk];
            fbl[t] = *(const bf16x8*)&Bsl[(wn + t * 16 + fr) * 32 + fk];
        }
#pragma unroll
        for (int mi = 0; mi < 4; ++mi)
#pragma unroll
            for (int ni = 0; ni < 4; ++ni) {
                acc[mi][ni] = __builtin_amdgcn_mfma_f32_16x16x32_bf16(fah[mi], fbh[ni], acc[mi][ni], 0, 0, 0);
                acc[mi][ni] = __builtin_amdgcn_mfma_f32_16x16x32_bf16(fah[mi], fbl[ni], acc[mi][ni], 0, 0, 0);
                acc[mi][ni] = __builtin_amdgcn_mfma_f32_16x16x32_bf16(fal[mi], fbh[ni], acc[mi][ni], 0, 0, 0);
            }
    }

    const int fr = lane & 15, fq = (lane >> 4) * 4;
    if (p.mode == 0) {
        float* C = p.Cf + (i64)z * p.sCz;
#pragma unroll
        for (int mi = 0; mi < 4; ++mi)
#pragma unroll
            for (int e = 0; e < 4; ++e) {
                const i64 row = m0 + wm + mi * 16 + fq + e;
#pragma unroll
                for (int ni = 0; ni < 4; ++ni)
                    C[row * p.ldc + n0 + wn + ni * 16 + fr] = acc[mi][ni][e];
            }
    } else if (p.mode == 1) {
        const i64 obase = (i64)z * IN_E;
#pragma unroll
        for (int mi = 0; mi < 4; ++mi)
#pragma unroll
            for (int e = 0; e < 4; ++e) {
                const i64 m = m0 + wm + mi * 16 + fq + e;
#pragma unroll
                for (int ni = 0; ni < 4; ++ni) {
                    const int c = (int)n0 + wn + ni * 16 + fr;
                    const int h = c >> 6, d = c & 63;
                    const i64 off = ((i64)h * SEQ + m) * DHEAD + d;
                    float v = acc[mi][ni][e];
                    if (z == 0) v += p.b1[c];
                    const u16 hb = f2bf(v);
                    const u16 lb = f2bf(v - bf2f(hb));
                    p.O1h[obase + off] = hb;
                    p.O1l[obase + off] = lb;
                    if (z == 0) {
                        const float v2 = acc[mi][ni][e] + p.b2[c];
                        const u16 hb2 = f2bf(v2);
                        const u16 lb2 = f2bf(v2 - bf2f(hb2));
                        p.O2h[off] = hb2;
                        p.O2l[off] = lb2;
                    }
                }
            }
    } else { // mode 2: exact GELU
        float* C = p.Cf;
#pragma unroll
        for (int mi = 0; mi < 4; ++mi)
#pragma unroll
            for (int e = 0; e < 4; ++e) {
                const i64 row = m0 + wm + mi * 16 + fq + e;
#pragma unroll
                for (int ni = 0; ni < 4; ++ni) {
                    const float x = acc[mi][ni][e];
                    C[row * p.ldc + n0 + wn + ni * 16 + fr] =
                        0.5f * x * (1.f + erff(x * 0.70710678118654752f));
                }
            }
    }
}

// ---------------------------------------------------------------------------
// PV: O[m, z*64+d] = sum_f W[z][m][f] * V[z][f][d]
// A = weights f32 (converted to hi/lo in-register, chop-split: exact remainder)
// B = vvT bf16 hi/lo [h][d][f]. Tile 256(M)x64(N), BK=32, 4 waves (64 rows each).
// Epilogue: split-store o_pre hi/lo.
// ---------------------------------------------------------------------------
__global__ __launch_bounds__(256)
void mfma_pv(const float* __restrict__ Wgt, const u16* __restrict__ VTh,
             const u16* __restrict__ VTl, u16* __restrict__ Oh, u16* __restrict__ Ol)
{
    __shared__ __align__(16) float Asf[256 * 32];
    __shared__ __align__(16) u16 Bsh[64 * 32];
    __shared__ __align__(16) u16 Bsl[64 * 32];
    const int tid = threadIdx.x, wave = tid >> 6, lane = tid & 63;
    const int z = blockIdx.z;
    const i64 m0 = (i64)blockIdx.y * 256;
    const float* A = Wgt + (i64)z * SEQ * SEQ;
    const u16* Bh = VTh + (i64)z * HEAD_E;
    const u16* Bl = VTl + (i64)z * HEAD_E;
    const int ar = tid >> 3, akc = (tid & 7) * 4;
    const int br = tid >> 2, bkc = (tid & 3) * 8;
    const int wm = wave * 64;
    f32x4 acc[4][4] = {};

    for (int k0 = 0; k0 < SEQ; k0 += 32) {
        __syncthreads();
#pragma unroll
        for (int i = 0; i < 8; ++i)
            gload16(A + (m0 + ar + i * 32) * SEQ + k0 + akc, &Asf[(i * 256 + wave * 64) * 4]);
        gload16(Bh + (i64)br * SEQ + k0 + bkc, &Bsh[wave * 512]);
        gload16(Bl + (i64)br * SEQ + k0 + bkc, &Bsl[wave * 512]);
        __syncthreads();
        const int fr = lane & 15, fk = (lane >> 4) * 8;
        bf16x8 fbh[4], fbl[4];
#pragma unroll
        for (int t = 0; t < 4; ++t) {
            fbh[t] = *(const bf16x8*)&Bsh[(t * 16 + fr) * 32 + fk];
            fbl[t] = *(const bf16x8*)&Bsl[(t * 16 + fr) * 32 + fk];
        }
#pragma unroll
        for (int mi = 0; mi < 4; ++mi) {
            const float4 x0 = *(const float4*)&Asf[(wm + mi * 16 + fr) * 32 + fk];
            const float4 x1 = *(const float4*)&Asf[(wm + mi * 16 + fr) * 32 + fk + 4];
            float av[8] = { x0.x, x0.y, x0.z, x0.w, x1.x, x1.y, x1.z, x1.w };
            bf16x8 ah, al;
#pragma unroll
            for (int j = 0; j < 8; ++j) {
                union { float f; unsigned u; } v; v.f = av[j];
                const u16 hb = (u16)(v.u >> 16);           // chop hi
                union { unsigned u; float f; } fh; fh.u = v.u & 0xFFFF0000u;
                union { float f; unsigned u; } rm; rm.f = av[j] - fh.f;  // exact
                ah[j] = (short)hb;
                al[j] = (short)(u16)(rm.u >> 16);          // chop lo
            }
#pragma unroll
            for (int ni = 0; ni < 4; ++ni) {
                acc[mi][ni] = __builtin_amdgcn_mfma_f32_16x16x32_bf16(ah, fbh[ni], acc[mi][ni], 0, 0, 0);
                acc[mi][ni] = __builtin_amdgcn_mfma_f32_16x16x32_bf16(ah, fbl[ni], acc[mi][ni], 0, 0, 0);
                acc[mi][ni] = __builtin_amdgcn_mfma_f32_16x16x32_bf16(al, fbh[ni], acc[mi][ni], 0, 0, 0);
            }
        }
    }

    const int fr = lane & 15, fq = (lane >> 4) * 4;
#pragma unroll
    for (int mi = 0; mi < 4; ++mi)
#pragma unroll
        for (int e = 0; e < 4; ++e) {
            const i64 m = m0 + wm + mi * 16 + fq + e;
#pragma unroll
            for (int ni = 0; ni < 4; ++ni) {
                const int c = z * 64 + ni * 16 + fr;
                const float v = acc[mi][ni][e];
                const u16 hb = f2bf(v);
                Oh[m * DMODEL + c] = hb;
                Ol[m * DMODEL + c] = f2bf(v - bf2f(hb));
            }
        }
}

// ---------------------------------------------------------------------------
// vv [h][f][d] -> vvT [h][d][f]  (bf16 hi+lo)
// ---------------------------------------------------------------------------
__global__ __launch_bounds__(256)
void transpose_vv(const u16* __restrict__ vh, const u16* __restrict__ vl,
                  u16* __restrict__ th, u16* __restrict__ tl)
{
    __shared__ u16 tile[64][65];
    const int tid = threadIdx.x;
    const int h = blockIdx.y, f0 = blockIdx.x * 64;
    const i64 src = ((i64)h * SEQ + f0) * DHEAD;
    const i64 dst = (i64)h * HEAD_E + f0;
#pragma unroll
    for (int i = 0; i < 16; ++i) {
        const int idx = i * 256 + tid;
        const int r = idx >> 6, c = idx & 63;
        tile[c][r] = vh[src + (i64)r * 64 + c];
    }
    __syncthreads();
#pragma unroll
    for (int i = 0; i < 16; ++i) {
        const int idx = i * 256 + tid;
        const int d = idx >> 6, fl = idx & 63;
        th[dst + (i64)d * SEQ + fl] = tile[d][fl];
    }
    __syncthreads();
#pragma unroll
    for (int i = 0; i < 16; ++i) {
        const int idx = i * 256 + tid;
        const int r = idx >> 6, c = idx & 63;
        tile[c][r] = vl[src + (i64)r * 64 + c];
    }
    __syncthreads();
#pragma unroll
    for (int i = 0; i < 16; ++i) {
        const int idx = i * 256 + tid;
        const int d = idx >> 6, fl = idx & 63;
        tl[dst + (i64)d * SEQ + fl] = tile[d][fl];
    }
}

// ---------------------------------------------------------------------------
// Row softmax (in-place on raw AC scores in d_out weights region).
// ---------------------------------------------------------------------------
__global__ __launch_bounds__(256)
void softmax_rows(float* __restrict__ Wbase, const float* __restrict__ Gbase,
                  const float* __restrict__ mask, unsigned int* __restrict__ lmin, int h0)
{
    __shared__ float red[4];
    const int hl = blockIdx.y;
    float* Wh = Wbase + (i64)(h0 + hl) * SEQ * SEQ;
    const float* G = Gbase + (i64)hl * SEQ * SEQ;
    const int i = blockIdx.x;
    const int tx = threadIdx.x;
    const i64 rowoff = (i64)i * SEQ;
    float s[8];
    float mloc = -3.0e38f;
#pragma unroll
    for (int r = 0; r < 8; ++r) {
        const int j = tx + (r << 8);
        float bd;
        if (j <= i)          bd = G[rowoff + (SEQ - 1 - i + j)];
        else if (j == i + 1) bd = 0.f;
        else                 bd = G[rowoff + SEQ + (j - i - 2)];
        const float v = (Wh[rowoff + j] + bd) * 0.03125f + mask[rowoff + j];
        s[r] = v;
        mloc = fmaxf(mloc, v);
    }
#pragma unroll
    for (int o = 32; o > 0; o >>= 1) mloc = fmaxf(mloc, __shfl_xor(mloc, o));
    if ((tx & 63) == 0) red[tx >> 6] = mloc;
    __syncthreads();
    const float m = fmaxf(fmaxf(red[0], red[1]), fmaxf(red[2], red[3]));
    __syncthreads();
    float lsum = 0.f;
#pragma unroll
    for (int r = 0; r < 8; ++r) { s[r] = __expf(s[r] - m); lsum += s[r]; }
#pragma unroll
    for (int o = 32; o > 0; o >>= 1) lsum += __shfl_xor(lsum, o);
    if ((tx & 63) == 0) red[tx >> 6] = lsum;
    __syncthreads();
    const float l = red[0] + red[1] + red[2] + red[3];
    const float inv = 1.f / l;
#pragma unroll
    for (int r = 0; r < 8; ++r) Wh[rowoff + tx + (r << 8)] = s[r] * inv;
    if (tx == 0) atomicMin(&lmin[h0 + hl], __float_as_uint(l));
}

__global__ void init_kernel(unsigned int* __restrict__ lmin)
{
    if (threadIdx.x < NHEADS) lmin[threadIdx.x] = 0x7F7FFFFFu;
}

__global__ void loss_kernel(const unsigned int* __restrict__ lmin, float* __restrict__ out)
{
    float v = 0.f;
    if (threadIdx.x < NHEADS) v = 1.f / __uint_as_float(lmin[threadIdx.x]);
#pragma unroll
    for (int o = 32; o > 0; o >>= 1) v += __shfl_xor(v, o);
    if (threadIdx.x == 0) *out = v * (1.f / NHEADS);
}

// ---------------------------------------------------------------------------
extern "C" void kernel_launch(void* const* d_in, const int* in_sizes, int n_in,
                              void* d_out, int out_size, void* d_ws, size_t ws_size,
                              hipStream_t stream)
{
    const float* query = (const float*)d_in[0];
    const float* key   = (const float*)d_in[1];
    const float* value = (const float*)d_in[2];
    const float* mask  = (const float*)d_in[3];
    const float* Wq    = (const float*)d_in[4];
    const float* Wke   = (const float*)d_in[5];
    const float* Wkr   = (const float*)d_in[6];
    const float* Wv    = (const float*)d_in[7];
    const float* Wf    = (const float*)d_in[8];
    const float* u_p   = (const float*)d_in[9];
    const float* v_p   = (const float*)d_in[10];

    float* out_final = (float*)d_out;
    float* weights   = out_final + (i64)SEQ * DMODEL;
    float* loss      = weights + (i64)NHEADS * SEQ * SEQ;

    // workspace layout
    char* w = (char*)d_ws;
    u16* in_h = (u16*)w;               w += (i64)4 * IN_E * 2;   // [query][key][value][rel]
    u16* in_l = (u16*)w;               w += (i64)4 * IN_E * 2;
    u16* W_h  = (u16*)w;               w += (i64)5 * W_E * 2;    // [Wq][Wke][Wv][Wkr][Wf]
    u16* W_l  = (u16*)w;               w += (i64)5 * W_E * 2;
    u16* P_h  = (u16*)w;               w += (i64)4 * IN_E * 2;   // [qu][kk][vv][rr]
    u16* P_l  = (u16*)w;               w += (i64)4 * IN_E * 2;
    u16* qv_h = (u16*)w;               w += (i64)IN_E * 2;
    u16* qv_l = (u16*)w;               w += (i64)IN_E * 2;
    u16* vvT_h = (u16*)w;              w += (i64)IN_E * 2;
    u16* vvT_l = (u16*)w;              w += (i64)IN_E * 2;
    u16* o_h  = (u16*)w;               w += (i64)IN_E * 2;
    u16* o_l  = (u16*)w;               w += (i64)IN_E * 2;
    unsigned int* lmin = (unsigned int*)w; w += 64;
    const i64 fixed_bytes = (i64)(w - (char*)d_ws);
    const i64 gbytes = (i64)SEQ * SEQ * 4;
    const i64 avail = (i64)ws_size - fixed_bytes;
    float* G;
    int chunk;
    if (avail >= gbytes) {
        G = (float*)w;
        i64 ch = avail / gbytes;
        chunk = ch > 16 ? 16 : (int)ch;
    } else {
        G = (float*)in_h;   // in-splits dead after projections; 32MB region
        chunk = 2;
    }

    dim3 blk(256);
    init_kernel<<<dim3(1), dim3(64), 0, stream>>>(lmin);

    // split inputs + weights
    SplitArgs sa;
    sa.src[0] = query; sa.dh[0] = in_h;           sa.dl[0] = in_l;           sa.n4[0] = IN_E / 4;
    sa.src[1] = key;   sa.dh[1] = in_h + IN_E;    sa.dl[1] = in_l + IN_E;    sa.n4[1] = IN_E / 4;
    sa.src[2] = value; sa.dh[2] = in_h + 2*IN_E;  sa.dl[2] = in_l + 2*IN_E;  sa.n4[2] = IN_E / 4;
    sa.src[3] = Wq;    sa.dh[3] = W_h;            sa.dl[3] = W_l;            sa.n4[3] = W_E / 4;
    sa.src[4] = Wke;   sa.dh[4] = W_h + W_E;      sa.dl[4] = W_l + W_E;      sa.n4[4] = W_E / 4;
    sa.src[5] = Wv;    sa.dh[5] = W_h + 2*W_E;    sa.dl[5] = W_l + 2*W_E;    sa.n4[5] = W_E / 4;
    sa.src[6] = Wkr;   sa.dh[6] = W_h + 3*W_E;    sa.dl[6] = W_l + 3*W_E;    sa.n4[6] = W_E / 4;
    sa.src[7] = Wf;    sa.dh[7] = W_h + 4*W_E;    sa.dl[7] = W_l + 4*W_E;    sa.n4[7] = W_E / 4;
    split_all<<<dim3(2048, 8), blk, 0, stream>>>(sa);
    posenc_split<<<dim3(IN_E / 256), blk, 0, stream>>>(in_h + 3*(i64)IN_E, in_l + 3*(i64)IN_E);

    // projections: z in {q,k,v,r}; A stride IN_E, B stride W_E, out stride IN_E
    {
        TNArgs p = {};
        p.Ah = in_h; p.Al = in_l; p.Bh = W_h; p.Bl = W_l;
        p.sAz = IN_E; p.sBz = W_E;
        p.O1h = P_h; p.O1l = P_l; p.O2h = qv_h; p.O2l = qv_l;
        p.b1 = u_p; p.b2 = v_p;
        p.K = DMODEL; p.mode = 1;
        mfma_tn128<<<dim3(DMODEL / 128, SEQ / 128, 4), blk, 0, stream>>>(p);
    }

    transpose_vv<<<dim3(SEQ / 64, NHEADS), blk, 0, stream>>>(
        P_h + 2*(i64)IN_E, P_l + 2*(i64)IN_E, vvT_h, vvT_l);

    // AC, all heads -> raw scores into weights region
    {
        TNArgs p = {};
        p.Ah = P_h; p.Al = P_l;                       // qu
        p.Bh = P_h + IN_E; p.Bl = P_l + IN_E;         // kk
        p.sAz = HEAD_E; p.sBz = HEAD_E;
        p.Cf = weights; p.sCz = (i64)SEQ * SEQ; p.ldc = SEQ;
        p.K = DHEAD; p.mode = 0;
        mfma_tn128<<<dim3(SEQ / 128, SEQ / 128, NHEADS), blk, 0, stream>>>(p);
    }

    // G + softmax in chunks
    for (int h0 = 0; h0 < NHEADS; h0 += chunk) {
        const int ch = (h0 + chunk <= NHEADS) ? chunk : (NHEADS - h0);
        TNArgs p = {};
        p.Ah = qv_h + (i64)h0 * HEAD_E; p.Al = qv_l + (i64)h0 * HEAD_E;
        p.Bh = P_h + 3*(i64)IN_E + (i64)h0 * HEAD_E;
        p.Bl = P_l + 3*(i64)IN_E + (i64)h0 * HEAD_E;
        p.sAz = HEAD_E; p.sBz = HEAD_E;
        p.Cf = G; p.sCz = (i64)SEQ * SEQ; p.ldc = SEQ;
        p.K = DHEAD; p.mode = 0;
        mfma_tn128<<<dim3(SEQ / 128, SEQ / 128, ch), blk, 0, stream>>>(p);
        softmax_rows<<<dim3(SEQ, ch), blk, 0, stream>>>(weights, G, mask, lmin, h0);
    }

    // PV
    mfma_pv<<<dim3(1, SEQ / 256, NHEADS), blk, 0, stream>>>(weights, vvT_h, vvT_l, o_h, o_l);

    // final GEMM + GELU
    {
        TNArgs p = {};
        p.Ah = o_h; p.Al = o_l;
        p.Bh = W_h + 4*(i64)W_E; p.Bl = W_l + 4*(i64)W_E;
        p.sAz = 0; p.sBz = 0;
        p.Cf = out_final; p.sCz = 0; p.ldc = DMODEL;
        p.K = DMODEL; p.mode = 2;
        mfma_tn128<<<dim3(DMODEL / 128, SEQ / 128, 1), blk, 0, stream>>>(p);
    }

    loss_kernel<<<dim3(1), dim3(64), 0, stream>>>(lmin, loss);
}